// Round 2
// baseline (117.587 us; speedup 1.0000x reference)
//
#include <hip/hip_runtime.h>
#include <hip/hip_bf16.h>

typedef __bf16 bf16t;
typedef bf16t bf16x8 __attribute__((ext_vector_type(8)));
typedef float f32x4 __attribute__((ext_vector_type(4)));
typedef unsigned short u16x4 __attribute__((ext_vector_type(4)));
typedef unsigned short u16x8 __attribute__((ext_vector_type(8)));

#define NB 2
#define NQ 2048
#define NK 2048
#define NH 16
#define ND 64
#define HD (NH * ND) /* 1024 */
#define QBLK 64
#define KVBLK 64
// (1/sqrt(64)) * log2(e): fold scale + base-2 conversion into Q.
#define SCALE_LOG2E 0.18033688011112042f

// One block = 64 q rows (4 waves x 16 rows) of one (b,h). Online softmax over
// KV tiles of 64. Swapped QK^T (mfma(K,Q) -> S^T) so lane owns scores of one
// q-row (q = lane&15); row reduce = shfl_xor(16), shfl_xor(32). P goes through
// a per-wave LDS tile to re-layout as the PV MFMA B-operand.
__global__ __launch_bounds__(256)
void scan_attn(const float* __restrict__ qs, const float* __restrict__ ks,
               const float* __restrict__ vs, const int* __restrict__ vlen,
               float* __restrict__ out)
{
    const int bid  = blockIdx.x;
    const int qt   = bid & 31;          // 32 q-tiles
    const int h    = (bid >> 5) & 15;   // 16 heads
    const int b    = bid >> 9;          // 2 batches
    const int tid  = threadIdx.x;
    const int wid  = tid >> 6;
    const int lane = tid & 63;
    const int g    = lane >> 4;         // 0..3
    const int ql   = lane & 15;         // q-row within wave tile
    const int q    = qt * QBLK + wid * 16 + ql;

    const int nkv    = vlen[b];                      // in [1, NK]
    const int ntiles = (nkv + KVBLK - 1) / KVBLK;    // only visit valid tiles

    const float* qptr = qs + ((size_t)b * NQ + q) * HD + h * ND;
    const float* kptr = ks + (size_t)b * NK * HD + h * ND;
    const float* vptr = vs + (size_t)b * NK * HD + h * ND;

    // Q fragments (B-operand of S^T mfma), 2 d-chunks of 32.
    bf16x8 qf[2];
#pragma unroll
    for (int c = 0; c < 2; ++c) {
        const float* p = qptr + 32 * c + 8 * g;
        f32x4 lo = *reinterpret_cast<const f32x4*>(p);
        f32x4 hi = *reinterpret_cast<const f32x4*>(p + 4);
#pragma unroll
        for (int j = 0; j < 4; ++j) {
            qf[c][j]     = (bf16t)(lo[j] * SCALE_LOG2E);
            qf[c][4 + j] = (bf16t)(hi[j] * SCALE_LOG2E);
        }
    }

    // Per-wave P tile [16 q][64 k], row padded to 72 ushorts (144 B: 16B-aligned
    // rows, and 2-way-max bank aliasing which is free).
    __shared__ __align__(16) unsigned short plds[4][16][72];

    float mrun = -__builtin_inff();
    float lrun = 0.0f;
    f32x4 o[4];
#pragma unroll
    for (int n = 0; n < 4; ++n) o[n] = (f32x4){0.f, 0.f, 0.f, 0.f};

    for (int t = 0; t < ntiles; ++t) {
        const int kb = t * KVBLK;

        // ---- S^T = K_tile . Q^T  (4 m-tiles of 16 k-rows, accumulate over d)
        f32x4 s[4];
#pragma unroll
        for (int m2 = 0; m2 < 4; ++m2) {
            f32x4 acc = (f32x4){0.f, 0.f, 0.f, 0.f};
#pragma unroll
            for (int c = 0; c < 2; ++c) {
                const float* p = kptr + (size_t)(kb + 16 * m2 + ql) * HD + 32 * c + 8 * g;
                f32x4 lo = *reinterpret_cast<const f32x4*>(p);
                f32x4 hi = *reinterpret_cast<const f32x4*>(p + 4);
                bf16x8 kf;
#pragma unroll
                for (int j = 0; j < 4; ++j) {
                    kf[j]     = (bf16t)lo[j];
                    kf[4 + j] = (bf16t)hi[j];
                }
                acc = __builtin_amdgcn_mfma_f32_16x16x32_bf16(kf, qf[c], acc, 0, 0, 0);
            }
            s[m2] = acc;  // s[m2][r] = S'[q=ql][k = kb+16*m2+4*g+r] (log2-domain)
        }

        // ---- mask tail + tile max
        float pmax = -__builtin_inff();
#pragma unroll
        for (int m2 = 0; m2 < 4; ++m2)
#pragma unroll
            for (int r = 0; r < 4; ++r) {
                const int kk = kb + 16 * m2 + 4 * g + r;
                float v = (kk < nkv) ? s[m2][r] : -__builtin_inff();
                s[m2][r] = v;
                pmax = fmaxf(pmax, v);
            }
        pmax = fmaxf(pmax, __shfl_xor(pmax, 16));
        pmax = fmaxf(pmax, __shfl_xor(pmax, 32));
        const float mnew  = fmaxf(mrun, pmax);       // always finite (tile has >=1 valid k)
        const float alpha = exp2f(mrun - mnew);

        // ---- p = 2^(s - mnew); write bf16 P to LDS; accumulate row sum of the
        // bf16-ROUNDED p so denominator matches the PV numerator exactly.
        float ps = 0.0f;
#pragma unroll
        for (int m2 = 0; m2 < 4; ++m2) {
            u16x4 pk;
#pragma unroll
            for (int r = 0; r < 4; ++r) {
                float pv = exp2f(s[m2][r] - mnew);
                bf16t pb = (bf16t)pv;
                ps += (float)pb;
                pk[r] = __builtin_bit_cast(unsigned short, pb);
            }
            *reinterpret_cast<u16x4*>(&plds[wid][ql][16 * m2 + 4 * g]) = pk;
        }
        ps += __shfl_xor(ps, 16);
        ps += __shfl_xor(ps, 32);
        lrun = lrun * alpha + ps;
        mrun = mnew;
#pragma unroll
        for (int n = 0; n < 4; ++n)
#pragma unroll
            for (int r = 0; r < 4; ++r) o[n][r] *= alpha;

        // ---- O^T += V^T . P^T  (2 k-chunks of 32, 4 d-tiles of 16)
#pragma unroll
        for (int kc = 0; kc < 2; ++kc) {
            bf16x8 pf = __builtin_bit_cast(bf16x8,
                *reinterpret_cast<const u16x8*>(&plds[wid][ql][32 * kc + 8 * g]));
            const float* vp = vptr + (size_t)(kb + 32 * kc + 8 * g) * HD + ql;
#pragma unroll
            for (int n = 0; n < 4; ++n) {
                bf16x8 vf;
#pragma unroll
                for (int j = 0; j < 8; ++j)
                    vf[j] = (bf16t)vp[j * HD + 16 * n];   // V[kb+32kc+8g+j][16n+ql]
                o[n] = __builtin_amdgcn_mfma_f32_16x16x32_bf16(vf, pf, o[n], 0, 0, 0);
            }
        }
        // No __syncthreads needed: each wave only touches plds[wid].
    }

    // ---- normalize + store: o[n][r] -> O[q=ql][d = 16n + 4g + r]
    const float inv = 1.0f / lrun;
    float* op = out + ((size_t)b * NQ + q) * HD + h * ND;
#pragma unroll
    for (int n = 0; n < 4; ++n)
#pragma unroll
        for (int r = 0; r < 4; ++r)
            op[16 * n + 4 * g + r] = o[n][r] * inv;
}

extern "C" void kernel_launch(void* const* d_in, const int* in_sizes, int n_in,
                              void* d_out, int out_size, void* d_ws, size_t ws_size,
                              hipStream_t stream)
{
    const float* qs   = (const float*)d_in[0];
    const float* ks   = (const float*)d_in[1];
    const float* vs   = (const float*)d_in[2];
    const int*   vlen = (const int*)d_in[3];
    float* out = (float*)d_out;

    dim3 grid(NB * NH * (NQ / QBLK));   // 1024 blocks
    dim3 block(256);
    scan_attn<<<grid, block, 0, stream>>>(qs, ks, vs, vlen, out);
}

// Round 3
// 72.466 us; speedup vs baseline: 1.6227x; 1.6227x over previous
//
#include <hip/hip_runtime.h>
#include <hip/hip_bf16.h>

typedef __bf16 bf16t;
typedef bf16t bf16x8 __attribute__((ext_vector_type(8)));
typedef float f32x4 __attribute__((ext_vector_type(4)));
typedef unsigned short u16x4 __attribute__((ext_vector_type(4)));
typedef unsigned short u16x8 __attribute__((ext_vector_type(8)));

#define NB 2
#define NQ 2048
#define NK 2048
#define NH 16
#define ND 64
#define HD (NH * ND) /* 1024 */
#define QBLK 64
#define KVBLK 64
// (1/sqrt(64)) * log2(e): fold scale + base-2 conversion into Q.
#define SCALE_LOG2E 0.18033688011112042f

// One block = 64 q rows (4 waves x 16 rows) of one (b,h). Online softmax over
// KV tiles of 64. K and V^T are cooperatively staged in LDS as bf16 (double
// buffered, register-prefetched). All LDS tiles use the XOR swizzle
// byte ^= ((row&7)<<4) so every ds_read_b128/ds_write_b128 runs at the
// bank floor. Swapped QK^T (mfma(K,Q) -> S^T) keeps softmax row-local
// (q = lane&15, reduce = 2x shfl_xor).
__global__ __launch_bounds__(256)
void scan_attn(const float* __restrict__ qs, const float* __restrict__ ks,
               const float* __restrict__ vs, const int* __restrict__ vlen,
               float* __restrict__ out)
{
    const int bid  = blockIdx.x;
    const int b    = bid & 1;           // interleave batches for load balance
    const int h    = (bid >> 1) & 15;
    const int qt   = bid >> 5;
    const int tid  = threadIdx.x;
    const int wid  = tid >> 6;
    const int lane = tid & 63;
    const int g    = lane >> 4;         // 0..3
    const int ql   = lane & 15;         // q-row within wave tile
    const int swq  = (ql & 7) << 4;     // row-XOR swizzle for fragment reads
    const int q    = qt * QBLK + wid * 16 + ql;

    const int nkv    = vlen[b];                    // in [1, NK]
    const int ntiles = (nkv + KVBLK - 1) >> 6;
    const int rem    = nkv & 63;                   // 0 -> last tile is full

    const float* qptr = qs + ((size_t)b * NQ + q) * HD + h * ND;
    const float* kptr = ks + (size_t)b * NK * HD + h * ND;
    const float* vptr = vs + (size_t)b * NK * HD + h * ND;

    // ---- LDS: double-buffered bf16 K [k][d] and V^T [d][k], XOR-swizzled
    __shared__ __align__(16) char k_lds[2][KVBLK * 64 * 2];   // 16 KB
    __shared__ __align__(16) char vt_lds[2][64 * KVBLK * 2];  // 16 KB
    // per-wave P tile [16 q][64 k], rows padded to 72 ushorts
    __shared__ __align__(16) unsigned short plds[4][16][72];  // 9 KB

    // ---- Q fragments (B-operand of S^T mfma), scale folded in
    bf16x8 qf[2];
#pragma unroll
    for (int c = 0; c < 2; ++c) {
        const float* p = qptr + 32 * c + 8 * g;
        f32x4 lo = *reinterpret_cast<const f32x4*>(p);
        f32x4 hi = *reinterpret_cast<const f32x4*>(p + 4);
#pragma unroll
        for (int j = 0; j < 4; ++j) {
            qf[c][j]     = (bf16t)(lo[j] * SCALE_LOG2E);
            qf[c][4 + j] = (bf16t)(hi[j] * SCALE_LOG2E);
        }
    }

    // ---- staging assignment
    const int skr  = tid >> 2;            // K: k-row 0..63
    const int skc  = (tid & 3) << 4;      // K: 16-float column chunk
    const int skc2 = skc * 2;             // bytes
    const int ksw  = (skr & 7) << 4;
    const int svd  = tid & 63;            // V: d column (coalesced global read)
    const int svk  = (tid >> 6) << 4;     // V: 16 k-rows per thread
    const int svk2 = svk * 2;             // bytes
    const int vsw  = (svd & 7) << 4;

    f32x4 kreg[4];
    float vreg[16];

    auto load_tile = [&](int kb) {
        const float* kp = kptr + (size_t)(kb + skr) * HD + skc;
#pragma unroll
        for (int i = 0; i < 4; ++i)
            kreg[i] = *reinterpret_cast<const f32x4*>(kp + 4 * i);
        const float* vp = vptr + (size_t)(kb + svk) * HD + svd;
#pragma unroll
        for (int j = 0; j < 16; ++j)
            vreg[j] = vp[(size_t)j * HD];
    };

    auto store_tile = [&](int buf) {
        u16x8 w0, w1;
#pragma unroll
        for (int i = 0; i < 4; ++i)
#pragma unroll
            for (int j = 0; j < 4; ++j) {
                const int e = 4 * i + j;
                const unsigned short u =
                    __builtin_bit_cast(unsigned short, (bf16t)kreg[i][j]);
                if (e < 8) w0[e] = u; else w1[e - 8] = u;
            }
        char* kb_ = k_lds[buf] + skr * 128;
        *reinterpret_cast<u16x8*>(kb_ + (skc2 ^ ksw))        = w0;
        *reinterpret_cast<u16x8*>(kb_ + ((skc2 + 16) ^ ksw)) = w1;

        u16x8 x0, x1;
#pragma unroll
        for (int j = 0; j < 16; ++j) {
            const unsigned short u =
                __builtin_bit_cast(unsigned short, (bf16t)vreg[j]);
            if (j < 8) x0[j] = u; else x1[j - 8] = u;
        }
        char* vb_ = vt_lds[buf] + svd * 128;
        *reinterpret_cast<u16x8*>(vb_ + (svk2 ^ vsw))        = x0;
        *reinterpret_cast<u16x8*>(vb_ + ((svk2 + 16) ^ vsw)) = x1;
    };

    float mrun = -__builtin_inff();
    float lrun = 0.0f;
    f32x4 o[4];
#pragma unroll
    for (int n = 0; n < 4; ++n) o[n] = (f32x4){0.f, 0.f, 0.f, 0.f};

    load_tile(0);
    store_tile(0);
    __syncthreads();

    int cur = 0;
    for (int t = 0; t < ntiles; ++t) {
        const int kb = t << 6;
        const bool has_next = (t + 1) < ntiles;
        if (has_next) load_tile(kb + KVBLK);   // issue early; waits land in store_tile

        // ---- S^T = K_tile . Q^T (log2 domain)
        const char* kbuf = k_lds[cur];
        f32x4 s[4];
#pragma unroll
        for (int m2 = 0; m2 < 4; ++m2) {
            f32x4 acc = (f32x4){0.f, 0.f, 0.f, 0.f};
            const char* krow = kbuf + (16 * m2 + ql) * 128;
#pragma unroll
            for (int c = 0; c < 2; ++c) {
                bf16x8 kf = *reinterpret_cast<const bf16x8*>(
                    krow + ((64 * c + 16 * g) ^ swq));
                acc = __builtin_amdgcn_mfma_f32_16x16x32_bf16(kf, qf[c], acc, 0, 0, 0);
            }
            s[m2] = acc;   // s[m2][r] = S'[ql][kb + 16*m2 + 4*g + r]
        }

        // ---- tail mask (uniform branch, at most one tile per block)
        if (rem && t == ntiles - 1) {
            const int krem = nkv - kb;
#pragma unroll
            for (int m2 = 0; m2 < 4; ++m2)
#pragma unroll
                for (int r = 0; r < 4; ++r)
                    if (16 * m2 + 4 * g + r >= krem) s[m2][r] = -__builtin_inff();
        }

        // ---- online softmax
        float pmax = -__builtin_inff();
#pragma unroll
        for (int m2 = 0; m2 < 4; ++m2)
#pragma unroll
            for (int r = 0; r < 4; ++r) pmax = fmaxf(pmax, s[m2][r]);
        pmax = fmaxf(pmax, __shfl_xor(pmax, 16));
        pmax = fmaxf(pmax, __shfl_xor(pmax, 32));
        const float mnew  = fmaxf(mrun, pmax);
        const float alpha = exp2f(mrun - mnew);

        float ps = 0.0f;
#pragma unroll
        for (int m2 = 0; m2 < 4; ++m2) {
            u16x4 pk;
#pragma unroll
            for (int r = 0; r < 4; ++r) {
                float pv = exp2f(s[m2][r] - mnew);
                bf16t pb = (bf16t)pv;
                ps += (float)pb;   // denominator matches bf16-rounded numerator
                pk[r] = __builtin_bit_cast(unsigned short, pb);
            }
            *reinterpret_cast<u16x4*>(&plds[wid][ql][16 * m2 + 4 * g]) = pk;
        }
        ps += __shfl_xor(ps, 16);
        ps += __shfl_xor(ps, 32);
        lrun = lrun * alpha + ps;
        mrun = mnew;
#pragma unroll
        for (int n = 0; n < 4; ++n)
#pragma unroll
            for (int r = 0; r < 4; ++r) o[n][r] *= alpha;

        // ---- O^T += V^T . P^T
        const char* vbuf = vt_lds[cur];
#pragma unroll
        for (int kc = 0; kc < 2; ++kc) {
            bf16x8 pf = __builtin_bit_cast(bf16x8,
                *reinterpret_cast<const u16x8*>(&plds[wid][ql][32 * kc + 8 * g]));
#pragma unroll
            for (int n = 0; n < 4; ++n) {
                bf16x8 vf = *reinterpret_cast<const bf16x8*>(
                    vbuf + (16 * n + ql) * 128 + ((64 * kc + 16 * g) ^ swq));
                o[n] = __builtin_amdgcn_mfma_f32_16x16x32_bf16(vf, pf, o[n], 0, 0, 0);
            }
        }

        if (has_next) store_tile(cur ^ 1);  // cvt + ds_write into the other buffer
        __syncthreads();
        cur ^= 1;
    }

    // ---- normalize + store: o[n][r] -> O[q=ql][d = 16n + 4g + r]
    const float inv = 1.0f / lrun;
    float* op = out + ((size_t)b * NQ + q) * HD + h * ND;
#pragma unroll
    for (int n = 0; n < 4; ++n)
#pragma unroll
        for (int r = 0; r < 4; ++r)
            op[16 * n + 4 * g + r] = o[n][r] * inv;
}

extern "C" void kernel_launch(void* const* d_in, const int* in_sizes, int n_in,
                              void* d_out, int out_size, void* d_ws, size_t ws_size,
                              hipStream_t stream)
{
    const float* qs   = (const float*)d_in[0];
    const float* ks   = (const float*)d_in[1];
    const float* vs   = (const float*)d_in[2];
    const int*   vlen = (const int*)d_in[3];
    float* out = (float*)d_out;

    dim3 grid(NB * NH * (NQ / QBLK));   // 1024 blocks
    dim3 block(256);
    scan_attn<<<grid, block, 0, stream>>>(qs, ks, vs, vlen, out);
}

// Round 4
// 61.437 us; speedup vs baseline: 1.9139x; 1.1795x over previous
//
#include <hip/hip_runtime.h>
#include <hip/hip_bf16.h>

typedef __bf16 bf16t;
typedef bf16t bf16x8 __attribute__((ext_vector_type(8)));
typedef float f32x4 __attribute__((ext_vector_type(4)));
typedef float f32x16 __attribute__((ext_vector_type(16)));
typedef unsigned short u16x8 __attribute__((ext_vector_type(8)));
typedef unsigned int u32x4 __attribute__((ext_vector_type(4)));

#define NB 2
#define NQ 2048
#define NK 2048
#define NH 16
#define ND 64
#define HD (NH * ND) /* 1024 */
#define KVBLK 64
// (1/sqrt(64)) * log2(e): fold scale + base-2 conversion into Q.
#define SCALE_LOG2E 0.18033688011112042f
#define RESCALE_THR 8.0f

// m214-style structure, D=64: 4 waves x 32 q-rows = 128 q per block.
// 32x32x16 MFMA, swapped QK^T (S^T = K.Q^T) so each lane-pair owns one q-row's
// scores; softmax fully in-register (cvt_pk + permlane32_swap builds the PV
// B-fragment; no P LDS round-trip). K and V^T staged in LDS bf16, double
// buffered, XOR-swizzled (byte ^= (row&7)<<4).
__device__ inline unsigned cvt_pk_bf16(float a, float b) {
    unsigned r;
    asm("v_cvt_pk_bf16_f32 %0, %1, %2" : "=v"(r) : "v"(a), "v"(b));
    return r;  // lo16 = bf16(a), hi16 = bf16(b)
}

__device__ inline void plswap(unsigned& a, unsigned& b) {
#if __has_builtin(__builtin_amdgcn_permlane32_swap)
    auto r = __builtin_amdgcn_permlane32_swap(a, b, false, false);
    a = r[0]; b = r[1];
#else
    const unsigned as = __shfl_xor((int)a, 32);
    const unsigned bs = __shfl_xor((int)b, 32);
    const bool hi = (threadIdx.x & 32) != 0;
    const unsigned na = hi ? bs : a;
    const unsigned nb = hi ? b : as;
    a = na; b = nb;
#endif
}

__global__ __launch_bounds__(256)
void scan_attn(const float* __restrict__ qs, const float* __restrict__ ks,
               const float* __restrict__ vs, const int* __restrict__ vlen,
               float* __restrict__ out)
{
    const int bid  = blockIdx.x;
    const int b    = bid & 1;           // interleave batches for load balance
    const int h    = (bid >> 1) & 15;
    const int qt   = bid >> 5;          // 0..15, 128 q-rows each
    const int tid  = threadIdx.x;
    const int wid  = tid >> 6;
    const int lane = tid & 63;
    const int ql   = lane & 31;         // q-col within wave tile
    const int hi   = lane >> 5;
    const int swq  = (ql & 7) << 4;     // row-XOR swizzle for fragment reads
    const int q    = qt * 128 + wid * 32 + ql;

    const int nkv    = vlen[b];                    // in [1, NK]
    const int ntiles = (nkv + KVBLK - 1) >> 6;
    const int rem    = nkv & 63;                   // 0 -> last tile is full

    const float* qptr = qs + ((size_t)b * NQ + q) * HD + h * ND;
    const float* kptr = ks + (size_t)b * NK * HD + h * ND;
    const float* vptr = vs + (size_t)b * NK * HD + h * ND;

    // ---- LDS: double-buffered bf16 K [k][d] and V^T [d][k], XOR-swizzled
    __shared__ __align__(16) char k_lds[2][KVBLK * 64 * 2];   // 16 KB
    __shared__ __align__(16) char vt_lds[2][64 * KVBLK * 2];  // 16 KB

    // ---- Q fragments (B-operand), scale folded in. qf[c]: d = 16c + 8*hi + j
    bf16x8 qf[4];
#pragma unroll
    for (int c = 0; c < 4; ++c) {
        const float* p = qptr + 16 * c + 8 * hi;
        f32x4 lo = *reinterpret_cast<const f32x4*>(p);
        f32x4 h4 = *reinterpret_cast<const f32x4*>(p + 4);
#pragma unroll
        for (int j = 0; j < 4; ++j) {
            qf[c][j]     = (bf16t)(lo[j] * SCALE_LOG2E);
            qf[c][4 + j] = (bf16t)(h4[j] * SCALE_LOG2E);
        }
    }

    // ---- staging assignment (256 threads stage 64x64 K and 64x64 V^T)
    const int skr  = tid >> 2;            // K: k-row 0..63
    const int skc2 = (tid & 3) << 5;      // K: 32-byte chunk (16 floats)
    const int ksw  = (skr & 7) << 4;
    const int svd  = tid & 63;            // V: d column (coalesced global read)
    const int svk2 = (tid >> 6) << 5;     // V: 16 k-rows -> 32 bytes
    const int vsw  = (svd & 7) << 4;

    f32x4 kreg[4];
    float vreg[16];

    auto load_tile = [&](int kb) {
        const float* kp = kptr + (size_t)(kb + skr) * HD + ((tid & 3) << 4);
#pragma unroll
        for (int i = 0; i < 4; ++i)
            kreg[i] = *reinterpret_cast<const f32x4*>(kp + 4 * i);
        const float* vp = vptr + (size_t)(kb + ((tid >> 6) << 4)) * HD + svd;
#pragma unroll
        for (int j = 0; j < 16; ++j)
            vreg[j] = vp[(size_t)j * HD];
    };

    auto store_tile = [&](int buf) {
        u16x8 w0, w1;
#pragma unroll
        for (int i = 0; i < 4; ++i)
#pragma unroll
            for (int j = 0; j < 4; ++j) {
                const int e = 4 * i + j;
                const unsigned short u =
                    __builtin_bit_cast(unsigned short, (bf16t)kreg[i][j]);
                if (e < 8) w0[e] = u; else w1[e - 8] = u;
            }
        char* kb_ = k_lds[buf] + skr * 128;
        *reinterpret_cast<u16x8*>(kb_ + (skc2 ^ ksw))        = w0;
        *reinterpret_cast<u16x8*>(kb_ + ((skc2 + 16) ^ ksw)) = w1;

        u16x8 x0, x1;
#pragma unroll
        for (int j = 0; j < 16; ++j) {
            const unsigned short u =
                __builtin_bit_cast(unsigned short, (bf16t)vreg[j]);
            if (j < 8) x0[j] = u; else x1[j - 8] = u;
        }
        char* vb_ = vt_lds[buf] + svd * 128;
        *reinterpret_cast<u16x8*>(vb_ + (svk2 ^ vsw))        = x0;
        *reinterpret_cast<u16x8*>(vb_ + ((svk2 + 16) ^ vsw)) = x1;
    };

    float mrun = -__builtin_inff();
    float lrun = 0.0f;
    f32x16 o[2] = {};

    load_tile(0);
    store_tile(0);
    __syncthreads();

    int cur = 0;
    for (int t = 0; t < ntiles; ++t) {
        const int kb = t << 6;
        const bool has_next = (t + 1) < ntiles;
        if (has_next) load_tile(kb + KVBLK);   // issue early; hide under compute

        // ---- S^T = K_tile . Q^T (log2 domain). s[h2][r]: q=ql,
        //      k = kb + 32*h2 + (r&3) + 8*(r>>2) + 4*hi
        const char* kbuf = k_lds[cur];
        f32x16 s[2];
#pragma unroll
        for (int h2 = 0; h2 < 2; ++h2) {
            f32x16 acc = {};
            const char* krow = kbuf + (32 * h2 + ql) * 128;
#pragma unroll
            for (int c = 0; c < 4; ++c) {
                bf16x8 kf = *reinterpret_cast<const bf16x8*>(
                    krow + ((32 * c + 16 * hi) ^ swq));
                acc = __builtin_amdgcn_mfma_f32_32x32x16_bf16(kf, qf[c], acc, 0, 0, 0);
            }
            s[h2] = acc;
        }

        // ---- tail mask (uniform branch, at most one tile per block)
        if (rem && t == ntiles - 1) {
            const int krem = nkv - kb;
#pragma unroll
            for (int h2 = 0; h2 < 2; ++h2)
#pragma unroll
                for (int r = 0; r < 16; ++r)
                    if (32 * h2 + (r & 3) + 8 * (r >> 2) + 4 * hi >= krem)
                        s[h2][r] = -__builtin_inff();
        }

        // ---- online softmax (in-register; row = lanes l and l^32)
        float pmax = -__builtin_inff();
#pragma unroll
        for (int h2 = 0; h2 < 2; ++h2)
#pragma unroll
            for (int r = 0; r < 16; ++r) pmax = fmaxf(pmax, s[h2][r]);
        pmax = fmaxf(pmax, __shfl_xor(pmax, 32));

        if (!__all(pmax <= mrun + RESCALE_THR)) {   // defer-max (T13)
            const float mnew  = fmaxf(mrun, pmax);
            const float alpha = exp2f(mrun - mnew);
            lrun *= alpha;
            o[0] *= alpha;
            o[1] *= alpha;
            mrun = mnew;
        }

        float ps = 0.0f;
#pragma unroll
        for (int h2 = 0; h2 < 2; ++h2)
#pragma unroll
            for (int r = 0; r < 16; ++r) {
                const float pv = exp2f(s[h2][r] - mrun);
                s[h2][r] = pv;
                ps += pv;
            }
        ps += __shfl_xor(ps, 32);
        lrun += ps;

        // ---- P -> PV B-fragments in-register (T12). Chunk c covers
        //      k = 16c..16c+15; lane element j <-> k = 16c + 8*hi + j.
        bf16x8 pf[4];
#pragma unroll
        for (int c = 0; c < 4; ++c) {
            const int h2 = c >> 1, r0 = (c & 1) * 8;
            unsigned a0 = cvt_pk_bf16(s[h2][r0 + 0], s[h2][r0 + 1]);
            unsigned b0 = cvt_pk_bf16(s[h2][r0 + 4], s[h2][r0 + 5]);
            plswap(a0, b0);   // a0 -> w0, b0 -> w2
            unsigned a1 = cvt_pk_bf16(s[h2][r0 + 2], s[h2][r0 + 3]);
            unsigned b1 = cvt_pk_bf16(s[h2][r0 + 6], s[h2][r0 + 7]);
            plswap(a1, b1);   // a1 -> w1, b1 -> w3
            pf[c] = __builtin_bit_cast(bf16x8, (u32x4){a0, a1, b0, b1});
        }

        // ---- O^T += V^T . P^T  (2 d-tiles x 4 k-chunks)
        const char* vbuf = vt_lds[cur];
#pragma unroll
        for (int dt = 0; dt < 2; ++dt) {
            const char* vrow = vbuf + (32 * dt + ql) * 128;
#pragma unroll
            for (int c = 0; c < 4; ++c) {
                bf16x8 vf = *reinterpret_cast<const bf16x8*>(
                    vrow + ((32 * c + 16 * hi) ^ swq));
                o[dt] = __builtin_amdgcn_mfma_f32_32x32x16_bf16(vf, pf[c], o[dt], 0, 0, 0);
            }
        }

        if (has_next) store_tile(cur ^ 1);  // cvt + ds_write into other buffer
        __syncthreads();
        cur ^= 1;
    }

    // ---- normalize + store: o[dt][r] -> O[q=ql][d = 32dt + (r&3)+8(r>>2)+4hi]
    const float inv = 1.0f / lrun;
    float* op = out + ((size_t)b * NQ + q) * HD + h * ND;
#pragma unroll
    for (int dt = 0; dt < 2; ++dt)
#pragma unroll
        for (int rg = 0; rg < 4; ++rg) {
            f32x4 w;
#pragma unroll
            for (int e = 0; e < 4; ++e) w[e] = o[dt][4 * rg + e] * inv;
            *reinterpret_cast<f32x4*>(op + 32 * dt + 8 * rg + 4 * hi) = w;
        }
}

extern "C" void kernel_launch(void* const* d_in, const int* in_sizes, int n_in,
                              void* d_out, int out_size, void* d_ws, size_t ws_size,
                              hipStream_t stream)
{
    const float* qs   = (const float*)d_in[0];
    const float* ks   = (const float*)d_in[1];
    const float* vs   = (const float*)d_in[2];
    const int*   vlen = (const int*)d_in[3];
    float* out = (float*)d_out;

    dim3 grid(NB * NH * (NQ / 128));   // 512 blocks
    dim3 block(256);
    scan_attn<<<grid, block, 0, stream>>>(qs, ks, vs, vlen, out);
}